// Round 2
// baseline (334.337 us; speedup 1.0000x reference)
//
#include <hip/hip_runtime.h>

typedef unsigned short u16;
typedef __attribute__((ext_vector_type(8))) short bf16x8;
typedef __attribute__((ext_vector_type(4))) float f32x4;

#define NT 256
#define BT 64

__device__ __forceinline__ float bu2f(u16 v) { return __uint_as_float(((unsigned)v) << 16); }
__device__ __forceinline__ u16 f2bu(float f) {
  unsigned u = __float_as_uint(f);
  u += 0x7FFF + ((u >> 16) & 1);
  return (u16)(u >> 16);
}
__device__ __forceinline__ float sigm(float x) { return 1.0f / (1.0f + __expf(-x)); }
__device__ __forceinline__ float tanh_(float x) {
  float ax = fabsf(x);
  float e = __expf(-2.0f * ax);
  float t = (1.0f - e) / (1.0f + e);
  return copysignf(t, x);
}
__device__ __forceinline__ uint2 pack4(float4 v) {
  return make_uint2((unsigned)f2bu(v.x) | ((unsigned)f2bu(v.y) << 16),
                    (unsigned)f2bu(v.z) | ((unsigned)f2bu(v.w) << 16));
}
// load 8 consecutive fp32 -> bf16x8 fragment (16B-aligned source required)
__device__ __forceinline__ bf16x8 ldw8(const float* p) {
  float4 a = *(const float4*)p;
  float4 b = *(const float4*)(p + 4);
  bf16x8 r;
  r[0] = (short)f2bu(a.x); r[1] = (short)f2bu(a.y); r[2] = (short)f2bu(a.z); r[3] = (short)f2bu(a.w);
  r[4] = (short)f2bu(b.x); r[5] = (short)f2bu(b.y); r[6] = (short)f2bu(b.z); r[7] = (short)f2bu(b.w);
  return r;
}

// fp32 scalar region offsets (in floats)
#define O_DW   0
#define O_PWW  9
#define O_PWB  25
#define O_S1DW 41
#define O_S1PW 89
#define O_S1PB 345
#define O_S2DW 361
#define O_S2PW 409
#define O_S2PB 665
#define O_B1   681
#define O_B2   937
#define O_FC1B 1193
#define O_FC2W 1225
#define O_FC2B 1257
// 1258 floats = 5032 B -> region rounded to 5056

#define R1 5056                    // 25984 B: xs[7872]bf16 | y0@+15744 f32[2560] ; later u1[64*11*16]bf16; later A2[64*136]bf16
#define R2 (5056 + 25984)          // 38912 B: pooled[64*19*16]bf16 ; later Z[64*136]bf16 + zz@+17408 f32[64*33]
#define R3 (R2 + 38912)            // 21504 B: A1[64*168]bf16
#define SMEM_TOTAL (R3 + 21504)    // 91456 B

__global__ __launch_bounds__(NT) void tenvad(
    const float* __restrict__ xg,
    const float* __restrict__ h1g, const float* __restrict__ c1g,
    const float* __restrict__ h2g, const float* __restrict__ c2g,
    const float* __restrict__ dwWg, const float* __restrict__ pwWg, const float* __restrict__ pwBg,
    const float* __restrict__ s1dwg, const float* __restrict__ s1pwg, const float* __restrict__ s1pbg,
    const float* __restrict__ s2dwg, const float* __restrict__ s2pwg, const float* __restrict__ s2pbg,
    const float* __restrict__ wih1, const float* __restrict__ whh1,
    const float* __restrict__ bih1, const float* __restrict__ bhh1,
    const float* __restrict__ wih2, const float* __restrict__ whh2,
    const float* __restrict__ bih2, const float* __restrict__ bhh2,
    const float* __restrict__ fc1wg, const float* __restrict__ fc1bg,
    const float* __restrict__ fc2wg, const float* __restrict__ fc2bg,
    float* __restrict__ out, int B)
{
  __shared__ __align__(16) unsigned char smem[SMEM_TOTAL];
  const int t = threadIdx.x;
  const int blk = blockIdx.x;
  const int base = blk * BT;

  float* sw   = (float*)smem;
  u16* xs     = (u16*)(smem + R1);
  float* y0   = (float*)(smem + R1 + 15744);
  u16* u1     = (u16*)(smem + R1);
  u16* A2     = (u16*)(smem + R1);
  u16* pooled = (u16*)(smem + R2);
  u16* Z      = (u16*)(smem + R2);
  float* zz   = (float*)(smem + R2 + 17408);
  u16* A1     = (u16*)(smem + R3);

  float* probO = out;
  float* h1o = out + B;
  float* c1o = out + B + B * 64;
  float* h2o = out + B + B * 128;
  float* c2o = out + B + B * 192;

  // ---- P0: weights/biases -> LDS fp32 ----
  for (int i = t; i < 9;   i += NT) sw[O_DW  +i] = dwWg[i];
  for (int i = t; i < 16;  i += NT) sw[O_PWW +i] = pwWg[i];
  for (int i = t; i < 16;  i += NT) sw[O_PWB +i] = pwBg[i];
  for (int i = t; i < 48;  i += NT) sw[O_S1DW+i] = s1dwg[i];
  for (int i = t; i < 256; i += NT) sw[O_S1PW+i] = s1pwg[i];
  for (int i = t; i < 16;  i += NT) sw[O_S1PB+i] = s1pbg[i];
  for (int i = t; i < 48;  i += NT) sw[O_S2DW+i] = s2dwg[i];
  for (int i = t; i < 256; i += NT) sw[O_S2PW+i] = s2pwg[i];
  for (int i = t; i < 16;  i += NT) sw[O_S2PB+i] = s2pbg[i];
  for (int i = t; i < 256; i += NT) sw[O_B1+i] = bih1[i] + bhh1[i];
  for (int i = t; i < 256; i += NT) sw[O_B2+i] = bih2[i] + bhh2[i];
  for (int i = t; i < 32;  i += NT) sw[O_FC1B+i] = fc1bg[i];
  for (int i = t; i < 32;  i += NT) sw[O_FC2W+i] = fc2wg[i];
  if (t == 0) sw[O_FC2B] = fc2bg[0];

  // ---- P1: stage x tile (fp32 -> bf16), lstm1_h into A1 cols 80..143, zero cols 144..159 ----
  {
    const float4* src = (const float4*)xg + (size_t)blk * 1968;  // 64*123/4
    for (int i = t; i < 1968; i += NT) {
      *(uint2*)(xs + i * 4) = pack4(src[i]);
    }
    const float4* hsrc = (const float4*)h1g + (size_t)blk * 1024;  // 64*64/4
    for (int i = t; i < 1024; i += NT) {
      int m = i >> 4, j4 = (i & 15) * 4;
      *(uint2*)(A1 + m * 168 + 80 + j4) = pack4(hsrc[i]);
    }
    for (int i = t; i < 256; i += NT) {
      int m = i >> 2, k4 = 144 + (i & 3) * 4;
      *(uint2*)(A1 + m * 168 + k4) = make_uint2(0u, 0u);
    }
  }
  __syncthreads();

  // ---- P2: depthwise 3x3 conv -> y0[64][40] (w<39) ----
  for (int i = t; i < 2560; i += NT) {
    int b = i / 40, w = i - b * 40;
    if (w < 39) {
      const u16* xb = xs + b * 123;
      float s = 0.f;
#pragma unroll
      for (int kh = 0; kh < 3; ++kh)
#pragma unroll
        for (int kw = 0; kw < 3; ++kw)
          s = fmaf(bu2f(xb[kh * 41 + w + kw]), sw[O_DW + kh * 3 + kw], s);
      y0[b * 40 + w] = s;
    }
  }
  __syncthreads();

  // ---- P3: pointwise(16) + relu + maxpool3s2 -> pooled[64][19][16] bf16 ----
  for (int i = t; i < 1216; i += NT) {
    int b = i / 19, p = i - b * 19;
    float a0 = y0[b * 40 + 2 * p], a1 = y0[b * 40 + 2 * p + 1], a2 = y0[b * 40 + 2 * p + 2];
    float mx = fmaxf(a0, fmaxf(a1, a2));
    float mn = fminf(a0, fminf(a1, a2));
    u16* dst = pooled + (b * 19 + p) * 16;
#pragma unroll
    for (int c = 0; c < 16; ++c) {
      float wv = sw[O_PWW + c];
      float v = fmaf(wv, (wv > 0.f ? mx : mn), sw[O_PWB + c]);
      dst[c] = f2bu(fmaxf(v, 0.f));
    }
  }
  __syncthreads();

  // ---- P4: sep1 dw (stride2, pad1) + pw + relu -> u1[64][11][16] (col10 = zero pad) ----
  for (int i = t; i < 704; i += NT) {
    int b = i / 11, qq = i - b * 11;
    u16* dst = u1 + (b * 11 + qq) * 16;
    if (qq == 10) {
#pragma unroll
      for (int c = 0; c < 16; ++c) dst[c] = 0;
    } else {
      float t1[16];
#pragma unroll
      for (int c = 0; c < 16; ++c) t1[c] = 0.f;
#pragma unroll
      for (int k = 0; k < 3; ++k) {
        int w = 2 * qq - 1 + k;
        if (w >= 0 && w < 19) {
          const u16* pr = pooled + (b * 19 + w) * 16;
#pragma unroll
          for (int c = 0; c < 16; ++c) t1[c] = fmaf(bu2f(pr[c]), sw[O_S1DW + c * 3 + k], t1[c]);
        }
      }
#pragma unroll
      for (int co = 0; co < 16; ++co) {
        float s = sw[O_S1PB + co];
#pragma unroll
        for (int ci = 0; ci < 16; ++ci) s = fmaf(t1[ci], sw[O_S1PW + co * 16 + ci], s);
        dst[co] = f2bu(fmaxf(s, 0.f));
      }
    }
  }
  __syncthreads();

  // ---- P5: sep2 dw (stride2) + pw + relu -> feat into A1 cols 0..79 ----
  for (int i = t; i < 320; i += NT) {
    int b = i / 5, r = i - b * 5;
    float v[16];
#pragma unroll
    for (int c = 0; c < 16; ++c) v[c] = 0.f;
#pragma unroll
    for (int k = 0; k < 3; ++k) {
      const u16* ur = u1 + (b * 11 + 2 * r + k) * 16;
#pragma unroll
      for (int c = 0; c < 16; ++c) v[c] = fmaf(bu2f(ur[c]), sw[O_S2DW + c * 3 + k], v[c]);
    }
    u16* dst = A1 + b * 168 + r * 16;
#pragma unroll
    for (int co = 0; co < 16; ++co) {
      float s = sw[O_S2PB + co];
#pragma unroll
      for (int ci = 0; ci < 16; ++ci) s = fmaf(v[ci], sw[O_S2PW + co * 16 + ci], s);
      dst[co] = f2bu(fmaxf(s, 0.f));
    }
  }
  __syncthreads();

  // ---- P6: stage lstm2_h into A2 cols 64..127 ----
  {
    const float4* hsrc = (const float4*)h2g + (size_t)blk * 1024;
    for (int i = t; i < 1024; i += NT) {
      int m = i >> 4, j4 = (i & 15) * 4;
      *(uint2*)(A2 + m * 136 + 64 + j4) = pack4(hsrc[i]);
    }
  }
  __syncthreads();

  const int w = t >> 6, lane = t & 63, q = lane >> 4, l15 = lane & 15;
  const int j = w * 16 + l15;  // hidden column this lane owns

  // ---- P7: gates1 = [feat|h1] @ [wih1|whh1]^T  (K=160 padded), then cell1 ----
  {
    f32x4 acc[4][4];
#pragma unroll
    for (int mt = 0; mt < 4; ++mt)
#pragma unroll
      for (int g = 0; g < 4; ++g) { acc[mt][g][0]=0.f; acc[mt][g][1]=0.f; acc[mt][g][2]=0.f; acc[mt][g][3]=0.f; }

    const float* rowIh[4]; const float* rowHh[4];
#pragma unroll
    for (int g = 0; g < 4; ++g) {
      int n = g * 64 + j;
      rowIh[g] = wih1 + n * 80;
      rowHh[g] = whh1 + n * 64;
    }
    const u16* aBase[4];
#pragma unroll
    for (int mt = 0; mt < 4; ++mt) aBase[mt] = A1 + (mt * 16 + l15) * 168 + q * 8;

#pragma unroll
    for (int kc = 0; kc < 5; ++kc) {
      int k0 = kc * 32;
      bf16x8 af[4], bfm[4];
#pragma unroll
      for (int mt = 0; mt < 4; ++mt) af[mt] = *(const bf16x8*)(aBase[mt] + k0);
#pragma unroll
      for (int g = 0; g < 4; ++g) {
        if (kc == 0)      bfm[g] = ldw8(rowIh[g] + q * 8);
        else if (kc == 1) bfm[g] = ldw8(rowIh[g] + 32 + q * 8);
        else if (kc == 2) {
          const float* p = (q < 2) ? (rowIh[g] + 64 + q * 8) : (rowHh[g] + (q - 2) * 8);
          bfm[g] = ldw8(p);
        }
        else if (kc == 3) bfm[g] = ldw8(rowHh[g] + 16 + q * 8);
        else {
          bf16x8 zv = {};
          if (q < 2) zv = ldw8(rowHh[g] + 48 + q * 8);
          bfm[g] = zv;
        }
      }
#pragma unroll
      for (int mt = 0; mt < 4; ++mt)
#pragma unroll
        for (int g = 0; g < 4; ++g)
          acc[mt][g] = __builtin_amdgcn_mfma_f32_16x16x32_bf16(af[mt], bfm[g], acc[mt][g], 0, 0, 0);
    }

    float bI = sw[O_B1 + j], bF = sw[O_B1 + 64 + j], bG = sw[O_B1 + 128 + j], bO = sw[O_B1 + 192 + j];
#pragma unroll
    for (int mt = 0; mt < 4; ++mt) {
#pragma unroll
      for (int r = 0; r < 4; ++r) {
        int m = mt * 16 + q * 4 + r;
        int b = base + m;
        float iv = acc[mt][0][r] + bI;
        float fv = acc[mt][1][r] + bF;
        float gv = acc[mt][2][r] + bG;
        float ov = acc[mt][3][r] + bO;
        float cold = c1g[b * 64 + j];
        float cn = sigm(fv) * cold + sigm(iv) * tanh_(gv);
        float hn = sigm(ov) * tanh_(cn);
        c1o[b * 64 + j] = cn;
        h1o[b * 64 + j] = hn;
        u16 hb = f2bu(hn);
        A2[m * 136 + j] = hb;        // lstm2 input cols 0..63
        Z[m * 136 + 64 + j] = hb;    // fc input cols 64..127 (z = [h2|h1])
      }
    }
  }
  __syncthreads();

  // ---- P8: gates2 = [h1|h2state] @ [wih2|whh2]^T (K=128), then cell2 ----
  {
    f32x4 acc[4][4];
#pragma unroll
    for (int mt = 0; mt < 4; ++mt)
#pragma unroll
      for (int g = 0; g < 4; ++g) { acc[mt][g][0]=0.f; acc[mt][g][1]=0.f; acc[mt][g][2]=0.f; acc[mt][g][3]=0.f; }

    const float* rowIh[4]; const float* rowHh[4];
#pragma unroll
    for (int g = 0; g < 4; ++g) {
      int n = g * 64 + j;
      rowIh[g] = wih2 + n * 64;
      rowHh[g] = whh2 + n * 64;
    }
    const u16* aBase[4];
#pragma unroll
    for (int mt = 0; mt < 4; ++mt) aBase[mt] = A2 + (mt * 16 + l15) * 136 + q * 8;

#pragma unroll
    for (int kc = 0; kc < 4; ++kc) {
      int k0 = kc * 32;
      bf16x8 af[4], bfm[4];
#pragma unroll
      for (int mt = 0; mt < 4; ++mt) af[mt] = *(const bf16x8*)(aBase[mt] + k0);
#pragma unroll
      for (int g = 0; g < 4; ++g) {
        if (kc == 0)      bfm[g] = ldw8(rowIh[g] + q * 8);
        else if (kc == 1) bfm[g] = ldw8(rowIh[g] + 32 + q * 8);
        else if (kc == 2) bfm[g] = ldw8(rowHh[g] + q * 8);
        else              bfm[g] = ldw8(rowHh[g] + 32 + q * 8);
      }
#pragma unroll
      for (int mt = 0; mt < 4; ++mt)
#pragma unroll
        for (int g = 0; g < 4; ++g)
          acc[mt][g] = __builtin_amdgcn_mfma_f32_16x16x32_bf16(af[mt], bfm[g], acc[mt][g], 0, 0, 0);
    }

    float bI = sw[O_B2 + j], bF = sw[O_B2 + 64 + j], bG = sw[O_B2 + 128 + j], bO = sw[O_B2 + 192 + j];
#pragma unroll
    for (int mt = 0; mt < 4; ++mt) {
#pragma unroll
      for (int r = 0; r < 4; ++r) {
        int m = mt * 16 + q * 4 + r;
        int b = base + m;
        float iv = acc[mt][0][r] + bI;
        float fv = acc[mt][1][r] + bF;
        float gv = acc[mt][2][r] + bG;
        float ov = acc[mt][3][r] + bO;
        float cold = c2g[b * 64 + j];
        float cn = sigm(fv) * cold + sigm(iv) * tanh_(gv);
        float hn = sigm(ov) * tanh_(cn);
        c2o[b * 64 + j] = cn;
        h2o[b * 64 + j] = hn;
        Z[m * 136 + j] = f2bu(hn);   // fc input cols 0..63
      }
    }
  }
  __syncthreads();

  // ---- P9: fc1 (Z[64][128] @ fc1_w[32][128]^T) + relu -> zz[64][33] fp32 ----
  {
    f32x4 accf[2];
#pragma unroll
    for (int nt = 0; nt < 2; ++nt) { accf[nt][0]=0.f; accf[nt][1]=0.f; accf[nt][2]=0.f; accf[nt][3]=0.f; }
    int m0 = w * 16;
#pragma unroll
    for (int kc = 0; kc < 4; ++kc) {
      int k0 = kc * 32;
      bf16x8 a = *(const bf16x8*)(Z + (m0 + l15) * 136 + k0 + q * 8);
#pragma unroll
      for (int nt = 0; nt < 2; ++nt) {
        int n = nt * 16 + l15;
        bf16x8 bfr = ldw8(fc1wg + n * 128 + k0 + q * 8);
        accf[nt] = __builtin_amdgcn_mfma_f32_16x16x32_bf16(a, bfr, accf[nt], 0, 0, 0);
      }
    }
#pragma unroll
    for (int nt = 0; nt < 2; ++nt) {
      int n = nt * 16 + l15;
#pragma unroll
      for (int r = 0; r < 4; ++r) {
        int m = m0 + q * 4 + r;
        zz[m * 33 + n] = fmaxf(accf[nt][r] + sw[O_FC1B + n], 0.f);
      }
    }
  }
  __syncthreads();

  // ---- P10: fc2 + sigmoid -> prob ----
  if (t < 64) {
    int m = t;
    float s = sw[O_FC2B];
#pragma unroll
    for (int k = 0; k < 32; ++k) s = fmaf(zz[m * 33 + k], sw[O_FC2W + k], s);
    probO[base + m] = sigm(s);
  }
}

extern "C" void kernel_launch(void* const* d_in, const int* in_sizes, int n_in,
                              void* d_out, int out_size, void* d_ws, size_t ws_size,
                              hipStream_t stream) {
  (void)n_in; (void)out_size; (void)d_ws; (void)ws_size;
  int B = in_sizes[0] / 123;
  dim3 grid(B / BT), block(NT);
  hipLaunchKernelGGL(tenvad, grid, block, 0, stream,
      (const float*)d_in[0], (const float*)d_in[1], (const float*)d_in[2],
      (const float*)d_in[3], (const float*)d_in[4],
      (const float*)d_in[5], (const float*)d_in[6], (const float*)d_in[7],
      (const float*)d_in[8], (const float*)d_in[9], (const float*)d_in[10],
      (const float*)d_in[11], (const float*)d_in[12], (const float*)d_in[13],
      (const float*)d_in[14], (const float*)d_in[15], (const float*)d_in[16], (const float*)d_in[17],
      (const float*)d_in[18], (const float*)d_in[19], (const float*)d_in[20], (const float*)d_in[21],
      (const float*)d_in[22], (const float*)d_in[23], (const float*)d_in[24], (const float*)d_in[25],
      (float*)d_out, B);
}